// Round 2
// baseline (379.501 us; speedup 1.0000x reference)
//
#include <hip/hip_runtime.h>
#include <hip/hip_cooperative_groups.h>
#include <stdint.h>

namespace cg = cooperative_groups;

// out[b,j] = bias[j] + sum_i [ mask*scale_base[i,j]*silu(x[b,i])
//            + mask*scale_fft[i,j]* sum_k ( cos(kx)fc0[j,i,k] + sin(kx)fc1[j,i,k] ) ]
// R15: collapse 3 launches -> 1 cooperative kernel (phases P/M/R + 2 grid.sync).
// Rationale: R14 showed prep+reduce are near-roofline (~13 us combined) yet
// total-main residual is ~60 us -> residual is per-launch/gap overhead, not
// kernel time. Phase M is byte-identical to R11/R13 kan_main2 (51.1 us best).
// Phase P maps each kc-group to pack ITS OWN Bp slice (same-XCD L2 locality).
// Failed escapes on main (do not retry): R7 VGPR clamp (spill), R8 B-dbuf
// (-1 block), R9 device fences in-loop (L2 inv), R12 full unroll (spill).

#define I_DIM 256
#define O_DIM 256
#define G_DIM 32
#define B_DIM 4096

#define BM 128
#define BN 128
#define KSPLIT 16
#define ICH 16                  // i's per K-chunk
#define PITCH 72                // fallback kernel only

typedef short s8v __attribute__((ext_vector_type(8)));
typedef float f4v __attribute__((ext_vector_type(4)));

__device__ __forceinline__ uint32_t pack2bf16(float a, float b) {  // RNE
  uint32_t ua = __builtin_bit_cast(uint32_t, a);
  uint32_t ub = __builtin_bit_cast(uint32_t, b);
  ua += 0x7FFFu + ((ua >> 16) & 1u);
  ub += 0x7FFFu + ((ub >> 16) & 1u);
  return (ua >> 16) | (ub & 0xFFFF0000u);
}
__device__ __forceinline__ unsigned short bf16_rne(float a) {      // RNE scalar
  uint32_t ua = __builtin_bit_cast(uint32_t, a);
  ua += 0x7FFFu + ((ua >> 16) & 1u);
  return (unsigned short)(ua >> 16);
}
// round-half-up: ~half the insts of RNE; absmax impact negligible (R7/R8)
__device__ __forceinline__ uint32_t pack2bf16_f(float a, float b) {
  uint32_t ua = __builtin_bit_cast(uint32_t, a) + 0x8000u;
  uint32_t ub = __builtin_bit_cast(uint32_t, b) + 0x8000u;
  return (ua >> 16) | (ub & 0xFFFF0000u);
}
__device__ __forceinline__ float silu_f(float v) { return v / (1.0f + __expf(-v)); }

// cos/sin Chebyshev features k=1..32 for one (row, half): 16 packed uint32
__device__ __forceinline__ void gen_feat(float xv, int half, uint32_t* fb) {
  float s, c;
  __sincosf(xv, &s, &c);
  const float m2 = 2.f * c;
  float f0 = half ? s : c;                       // k=1
  float f1 = m2 * f0 - (half ? 0.f : 1.f);       // k=2
  fb[0] = pack2bf16_f(f0, f1);
  #pragma unroll
  for (int p = 1; p < 16; ++p) {
    float f2 = m2 * f1 - f0;
    float f3 = m2 * f2 - f1;
    fb[p] = pack2bf16_f(f2, f3);
    f0 = f2; f1 = f3;
  }
}

// ================================================ R15 fused cooperative kernel
// grid 1024 x 256, 4 blk/CU (co-resident: LDS 32KB -> 5/CU cap).
// P: pack Bp (each kc-group packs its own slice)  | sync
// M: byte-identical kan_main2 GEMM -> partial      | sync
// R: reduce partial -> out (4 outputs/thread)
__global__ __launch_bounds__(256, 4) void kan_fused(
    const float* __restrict__ x, const float* __restrict__ fc,
    const float* __restrict__ bias, const float* __restrict__ mask,
    const float* __restrict__ scale_base, const float* __restrict__ sfft,
    short* __restrict__ Bp, unsigned short* __restrict__ partial,
    float* __restrict__ out)
{
  __shared__ short A_lds[BM * 64];        // 16 KB, XOR-chunk swizzled
  __shared__ short B_lds[BN * 64];        // 16 KB, DMA image (pre-swizzled)

  const int tid = threadIdx.x;
  const int bx  = blockIdx.x;
  const int kc  = bx & 15;                // XCD affinity: Bp slice L2-resident

  // ---------------- phase P: pack this kc-group's Bp slice (i in [16kc,16kc+16))
  {
    const int g  = (bx >> 4) * 256 + tid;  // 0..16383 within kc-group
    const int h  = g & 1;                  // half of G row
    const int d  = (g >> 1) & 1;           // cos / sin
    const int pl = g >> 2;                 // il*256 + j
    const int j  = pl & 255;
    const int i  = kc * ICH + (pl >> 8);
    const int p  = i * 256 + j;
    const size_t ij = (size_t)i * O_DIM + j;
    const float sf = sfft[ij] * mask[ij];
    const float* src = fc + (size_t)d * (O_DIM * I_DIM * G_DIM)
                          + ((size_t)j * I_DIM + i) * G_DIM + h * 16;
    uint32_t w[8];
    #pragma unroll
    for (int q = 0; q < 4; ++q) {
      float4 v = ((const float4*)src)[q];
      w[2*q]   = pack2bf16(v.x * sf, v.y * sf);
      w[2*q+1] = pack2bf16(v.z * sf, v.w * sf);
    }
    uint4* dst = (uint4*)(Bp + (size_t)p * 64);
    const int xr2 = j & 7;
    #pragma unroll
    for (int c = 0; c < 2; ++c)
      dst[(4 * d + 2 * h + c) ^ xr2] = make_uint4(w[4*c], w[4*c+1], w[4*c+2], w[4*c+3]);
  }

  cg::this_grid().sync();                 // Bp visible grid-wide

  // ---------------- phase M: byte-identical to kan_main2 (R11/R13 operating point)
  {
    const int bn  = (bx >> 4) & 1;
    const int bm  = bx >> 5;
    const int i0  = kc * ICH;

    const int lane = tid & 63;
    const int wave = tid >> 6;
    const int wm   = wave & 1;
    const int wn   = wave >> 1;
    const int l15  = lane & 15;
    const int quad = lane >> 4;

    f4v acc[4][4];
    #pragma unroll
    for (int a = 0; a < 4; ++a)
      #pragma unroll
      for (int b = 0; b < 4; ++b)
        acc[a][b] = (f4v){0.f, 0.f, 0.f, 0.f};

    const int row  = tid >> 1;
    const int half = tid & 1;
    const int mg   = bm * BM + row;
    const int jg   = bn * BN + row;
    const int xr   = row & 7;

    const float* xrow = x + (size_t)mg * I_DIM + i0;
    uint4* Arow = (uint4*)&A_lds[row * 64];
    const int c0 = half * 4;                // this thread's 4 A-chunks
    const int q0 = wave * 4;                // 4 DMA insts per wave
    const size_t dma_lane_off = (size_t)lane * 8;

    uint32_t aNext[16];
    gen_feat(xrow[0], half, aNext);

    for (int it = 0; it < ICH; ++it) {
      __syncthreads();                      // readers of it-1 done

      // A: store regs generated during previous MFMA phase (swizzled slots)
      Arow[(c0 + 0) ^ xr] = make_uint4(aNext[0],  aNext[1],  aNext[2],  aNext[3]);
      Arow[(c0 + 1) ^ xr] = make_uint4(aNext[4],  aNext[5],  aNext[6],  aNext[7]);
      Arow[(c0 + 2) ^ xr] = make_uint4(aNext[8],  aNext[9],  aNext[10], aNext[11]);
      Arow[(c0 + 3) ^ xr] = make_uint4(aNext[12], aNext[13], aNext[14], aNext[15]);

      // B: direct HBM/L2/L3 -> LDS DMA (after ds_writes: no alias-order stall).
      {
        const size_t rbase = ((size_t)(i0 + it) * 256 + bn * BN) * 64;
        #pragma unroll
        for (int c = 0; c < 4; ++c) {
          const int q = q0 + c;
          const short* g = Bp + rbase + (size_t)q * 8 * 64 + dma_lane_off;
          __builtin_amdgcn_global_load_lds(
              (const __attribute__((address_space(1))) void*)g,
              (__attribute__((address_space(3))) void*)&B_lds[q * 8 * 64],
              16, 0, 0);
        }
      }

      __syncthreads();                      // drains vmcnt (DMA) + lgkm (A writes)

      if (it + 1 < ICH) gen_feat(xrow[it + 1], half, aNext);  // overlaps MFMA below

      #pragma unroll
      for (int ks = 0; ks < 2; ++ks) {
        s8v a[4], b[4];
        #pragma unroll
        for (int tm = 0; tm < 4; ++tm) {
          const int r = wm * 64 + tm * 16 + l15;
          a[tm] = *(const s8v*)&A_lds[r * 64 + (((ks * 4 + quad) ^ (r & 7)) * 8)];
        }
        #pragma unroll
        for (int tn = 0; tn < 4; ++tn) {
          const int r = wn * 64 + tn * 16 + l15;
          b[tn] = *(const s8v*)&B_lds[r * 64 + (((ks * 4 + quad) ^ (r & 7)) * 8)];
        }
        #pragma unroll
        for (int tm = 0; tm < 4; ++tm)
          #pragma unroll
          for (int tn = 0; tn < 4; ++tn)
            acc[tm][tn] = __builtin_amdgcn_mfma_f32_16x16x32_bf16(a[tm], b[tn], acc[tm][tn], 0, 0, 0);
      }
    }

    // -------- base tile: K=32 (16 silu features + 16 zeros)
    __syncthreads();
    {
      const float* xb = xrow + half * 8;
      float4 v0 = ((const float4*)xb)[0];
      float4 v1 = ((const float4*)xb)[1];
      uint32_t a0 = pack2bf16(silu_f(v0.x), silu_f(v0.y));
      uint32_t a1 = pack2bf16(silu_f(v0.z), silu_f(v0.w));
      uint32_t a2 = pack2bf16(silu_f(v1.x), silu_f(v1.y));
      uint32_t a3 = pack2bf16(silu_f(v1.z), silu_f(v1.w));
      Arow[half ^ xr]       = make_uint4(a0, a1, a2, a3);
      Arow[(2 + half) ^ xr] = make_uint4(0, 0, 0, 0);

      uint32_t w[4];
      #pragma unroll
      for (int p = 0; p < 4; ++p) {
        const int ia = i0 + half * 8 + 2 * p;
        const size_t o0 = (size_t)ia * O_DIM + jg;
        const size_t o1 = o0 + O_DIM;
        w[p] = pack2bf16(scale_base[o0] * mask[o0], scale_base[o1] * mask[o1]);
      }
      uint4* Brow = (uint4*)&B_lds[row * 64];
      Brow[half ^ xr]       = make_uint4(w[0], w[1], w[2], w[3]);
      Brow[(2 + half) ^ xr] = make_uint4(0, 0, 0, 0);
    }
    __syncthreads();
    {
      s8v a[4], b[4];
      #pragma unroll
      for (int tm = 0; tm < 4; ++tm) {
        const int r = wm * 64 + tm * 16 + l15;
        a[tm] = *(const s8v*)&A_lds[r * 64 + ((quad ^ (r & 7)) * 8)];
      }
      #pragma unroll
      for (int tn = 0; tn < 4; ++tn) {
        const int r = wn * 64 + tn * 16 + l15;
        b[tn] = *(const s8v*)&B_lds[r * 64 + ((quad ^ (r & 7)) * 8)];
      }
      #pragma unroll
      for (int tm = 0; tm < 4; ++tm)
        #pragma unroll
        for (int tn = 0; tn < 4; ++tn)
          acc[tm][tn] = __builtin_amdgcn_mfma_f32_16x16x32_bf16(a[tm], b[tn], acc[tm][tn], 0, 0, 0);
    }

    // -------- epilogue: coalesced bf16 partial stores (RNE, once/block)
    unsigned short* pbase = partial + (size_t)kc * B_DIM * O_DIM;
    #pragma unroll
    for (int tm = 0; tm < 4; ++tm) {
      #pragma unroll
      for (int tn = 0; tn < 4; ++tn) {
        const int n_g = bn * BN + wn * 64 + tn * 16 + l15;
        f4v v = acc[tm][tn];
        #pragma unroll
        for (int r = 0; r < 4; ++r) {
          const int m_g = bm * BM + wm * 64 + tm * 16 + quad * 4 + r;
          pbase[(size_t)m_g * O_DIM + n_g] = bf16_rne(v[r]);
        }
      }
    }
  }

  cg::this_grid().sync();                 // partial visible grid-wide

  // ---------------- phase R: reduce 16 partial slices -> out (4 outputs/thread)
  {
    const int g  = bx * 256 + tid;        // 262144 threads
    const int m  = g >> 6;
    const int n4 = (g & 63) << 2;
    const unsigned short* pp = partial + (size_t)m * O_DIM + n4;
    float4 b4 = ((const float4*)(bias + n4))[0];
    float a0 = b4.x, a1 = b4.y, a2 = b4.z, a3 = b4.w;
    #pragma unroll
    for (int k2 = 0; k2 < KSPLIT; ++k2) {
      const uint2 v = *(const uint2*)(pp + (size_t)k2 * (B_DIM * O_DIM));
      a0 += __builtin_bit_cast(float, v.x << 16);
      a1 += __builtin_bit_cast(float, v.x & 0xFFFF0000u);
      a2 += __builtin_bit_cast(float, v.y << 16);
      a3 += __builtin_bit_cast(float, v.y & 0xFFFF0000u);
    }
    ((float4*)(out + (size_t)m * O_DIM + n4))[0] = make_float4(a0, a1, a2, a3);
  }
}

// ================================================ proven 3-kernel path (R14)
// kept as runtime fallback if cooperative launch is rejected

__global__ __launch_bounds__(256) void prep_bs_kernel(
    const float* __restrict__ fc, const float* __restrict__ mask,
    const float* __restrict__ sfft, short* __restrict__ Bp)
{
  const int gid = blockIdx.x * 256 + threadIdx.x;   // 262144 threads
  const int h = gid & 1;
  const int d = (gid >> 1) & 1;
  const int p = gid >> 2;
  const int i = p >> 8, j = p & 255;
  const size_t ij = (size_t)i * O_DIM + j;
  const float sf = sfft[ij] * mask[ij];
  const float* src = fc + (size_t)d * (O_DIM * I_DIM * G_DIM)
                        + ((size_t)j * I_DIM + i) * G_DIM + h * 16;
  uint32_t w[8];
  #pragma unroll
  for (int q = 0; q < 4; ++q) {
    float4 v = ((const float4*)src)[q];
    w[2*q]   = pack2bf16(v.x * sf, v.y * sf);
    w[2*q+1] = pack2bf16(v.z * sf, v.w * sf);
  }
  uint4* dst = (uint4*)(Bp + (size_t)p * 64);
  const int xr = j & 7;
  #pragma unroll
  for (int c = 0; c < 2; ++c)
    dst[(4 * d + 2 * h + c) ^ xr] = make_uint4(w[4*c], w[4*c+1], w[4*c+2], w[4*c+3]);
}

__global__ __launch_bounds__(256, 4) void kan_main2(
    const float* __restrict__ x,
    const short* __restrict__ Bp,
    const float* __restrict__ mask,
    const float* __restrict__ scale_base,
    unsigned short* __restrict__ partial) // (16, 4096, 256) bf16
{
  __shared__ short A_lds[BM * 64];
  __shared__ short B_lds[BN * 64];

  const int tid = threadIdx.x;
  const int bx  = blockIdx.x;
  const int kc  = bx & 15;
  const int bn  = (bx >> 4) & 1;
  const int bm  = bx >> 5;
  const int i0  = kc * ICH;

  const int lane = tid & 63;
  const int wave = tid >> 6;
  const int wm   = wave & 1;
  const int wn   = wave >> 1;
  const int l15  = lane & 15;
  const int quad = lane >> 4;

  f4v acc[4][4];
  #pragma unroll
  for (int a = 0; a < 4; ++a)
    #pragma unroll
    for (int b = 0; b < 4; ++b)
      acc[a][b] = (f4v){0.f, 0.f, 0.f, 0.f};

  const int row  = tid >> 1;
  const int half = tid & 1;
  const int mg   = bm * BM + row;
  const int jg   = bn * BN + row;
  const int xr   = row & 7;

  const float* xrow = x + (size_t)mg * I_DIM + i0;
  uint4* Arow = (uint4*)&A_lds[row * 64];
  const int c0 = half * 4;
  const int q0 = wave * 4;
  const size_t dma_lane_off = (size_t)lane * 8;

  uint32_t aNext[16];
  gen_feat(xrow[0], half, aNext);

  for (int it = 0; it < ICH; ++it) {
    __syncthreads();

    Arow[(c0 + 0) ^ xr] = make_uint4(aNext[0],  aNext[1],  aNext[2],  aNext[3]);
    Arow[(c0 + 1) ^ xr] = make_uint4(aNext[4],  aNext[5],  aNext[6],  aNext[7]);
    Arow[(c0 + 2) ^ xr] = make_uint4(aNext[8],  aNext[9],  aNext[10], aNext[11]);
    Arow[(c0 + 3) ^ xr] = make_uint4(aNext[12], aNext[13], aNext[14], aNext[15]);

    {
      const size_t rbase = ((size_t)(i0 + it) * 256 + bn * BN) * 64;
      #pragma unroll
      for (int c = 0; c < 4; ++c) {
        const int q = q0 + c;
        const short* g = Bp + rbase + (size_t)q * 8 * 64 + dma_lane_off;
        __builtin_amdgcn_global_load_lds(
            (const __attribute__((address_space(1))) void*)g,
            (__attribute__((address_space(3))) void*)&B_lds[q * 8 * 64],
            16, 0, 0);
      }
    }

    __syncthreads();

    if (it + 1 < ICH) gen_feat(xrow[it + 1], half, aNext);

    #pragma unroll
    for (int ks = 0; ks < 2; ++ks) {
      s8v a[4], b[4];
      #pragma unroll
      for (int tm = 0; tm < 4; ++tm) {
        const int r = wm * 64 + tm * 16 + l15;
        a[tm] = *(const s8v*)&A_lds[r * 64 + (((ks * 4 + quad) ^ (r & 7)) * 8)];
      }
      #pragma unroll
      for (int tn = 0; tn < 4; ++tn) {
        const int r = wn * 64 + tn * 16 + l15;
        b[tn] = *(const s8v*)&B_lds[r * 64 + (((ks * 4 + quad) ^ (r & 7)) * 8)];
      }
      #pragma unroll
      for (int tm = 0; tm < 4; ++tm)
        #pragma unroll
        for (int tn = 0; tn < 4; ++tn)
          acc[tm][tn] = __builtin_amdgcn_mfma_f32_16x16x32_bf16(a[tm], b[tn], acc[tm][tn], 0, 0, 0);
    }
  }

  __syncthreads();
  {
    const float* xb = xrow + half * 8;
    float4 v0 = ((const float4*)xb)[0];
    float4 v1 = ((const float4*)xb)[1];
    uint32_t a0 = pack2bf16(silu_f(v0.x), silu_f(v0.y));
    uint32_t a1 = pack2bf16(silu_f(v0.z), silu_f(v0.w));
    uint32_t a2 = pack2bf16(silu_f(v1.x), silu_f(v1.y));
    uint32_t a3 = pack2bf16(silu_f(v1.z), silu_f(v1.w));
    Arow[half ^ xr]       = make_uint4(a0, a1, a2, a3);
    Arow[(2 + half) ^ xr] = make_uint4(0, 0, 0, 0);

    uint32_t w[4];
    #pragma unroll
    for (int p = 0; p < 4; ++p) {
      const int ia = i0 + half * 8 + 2 * p;
      const size_t o0 = (size_t)ia * O_DIM + jg;
      const size_t o1 = o0 + O_DIM;
      w[p] = pack2bf16(scale_base[o0] * mask[o0], scale_base[o1] * mask[o1]);
    }
    uint4* Brow = (uint4*)&B_lds[row * 64];
    Brow[half ^ xr]       = make_uint4(w[0], w[1], w[2], w[3]);
    Brow[(2 + half) ^ xr] = make_uint4(0, 0, 0, 0);
  }
  __syncthreads();
  {
    s8v a[4], b[4];
    #pragma unroll
    for (int tm = 0; tm < 4; ++tm) {
      const int r = wm * 64 + tm * 16 + l15;
      a[tm] = *(const s8v*)&A_lds[r * 64 + ((quad ^ (r & 7)) * 8)];
    }
    #pragma unroll
    for (int tn = 0; tn < 4; ++tn) {
      const int r = wn * 64 + tn * 16 + l15;
      b[tn] = *(const s8v*)&B_lds[r * 64 + ((quad ^ (r & 7)) * 8)];
    }
    #pragma unroll
    for (int tm = 0; tm < 4; ++tm)
      #pragma unroll
      for (int tn = 0; tn < 4; ++tn)
        acc[tm][tn] = __builtin_amdgcn_mfma_f32_16x16x32_bf16(a[tm], b[tn], acc[tm][tn], 0, 0, 0);
  }

  unsigned short* pbase = partial + (size_t)kc * B_DIM * O_DIM;
  #pragma unroll
  for (int tm = 0; tm < 4; ++tm) {
    #pragma unroll
    for (int tn = 0; tn < 4; ++tn) {
      const int n_g = bn * BN + wn * 64 + tn * 16 + l15;
      f4v v = acc[tm][tn];
      #pragma unroll
      for (int r = 0; r < 4; ++r) {
        const int m_g = bm * BM + wm * 64 + tm * 16 + quad * 4 + r;
        pbase[(size_t)m_g * O_DIM + n_g] = bf16_rne(v[r]);
      }
    }
  }
}

__global__ __launch_bounds__(256) void reduce_kernel(
    const unsigned short* __restrict__ partial, const float* __restrict__ bias,
    float* __restrict__ out)
{
  const int g  = blockIdx.x * 256 + threadIdx.x;   // 131072 threads
  const int m  = g >> 5;
  const int n8 = (g & 31) << 3;
  const unsigned short* p = partial + (size_t)m * O_DIM + n8;

  float acc[8];
  {
    float4 b0 = ((const float4*)(bias + n8))[0];
    float4 b1 = ((const float4*)(bias + n8))[1];
    acc[0] = b0.x; acc[1] = b0.y; acc[2] = b0.z; acc[3] = b0.w;
    acc[4] = b1.x; acc[5] = b1.y; acc[6] = b1.z; acc[7] = b1.w;
  }
  #pragma unroll
  for (int kc = 0; kc < KSPLIT; ++kc) {
    const uint4 v = *(const uint4*)(p + (size_t)kc * (B_DIM * O_DIM));
    acc[0] += __builtin_bit_cast(float, v.x << 16);
    acc[1] += __builtin_bit_cast(float, v.x & 0xFFFF0000u);
    acc[2] += __builtin_bit_cast(float, v.y << 16);
    acc[3] += __builtin_bit_cast(float, v.y & 0xFFFF0000u);
    acc[4] += __builtin_bit_cast(float, v.z << 16);
    acc[5] += __builtin_bit_cast(float, v.z & 0xFFFF0000u);
    acc[6] += __builtin_bit_cast(float, v.w << 16);
    acc[7] += __builtin_bit_cast(float, v.w & 0xFFFF0000u);
  }
  float* o = out + (size_t)m * O_DIM + n8;
  ((float4*)o)[0] = make_float4(acc[0], acc[1], acc[2], acc[3]);
  ((float4*)o)[1] = make_float4(acc[4], acc[5], acc[6], acc[7]);
}

// ================================================ ws-free atomic fallback (R2)
__global__ __launch_bounds__(256, 4) void kan_fft_fallback(
    const float* __restrict__ x, const float* __restrict__ fc,
    const float* __restrict__ bias, const float* __restrict__ mask,
    const float* __restrict__ scale_base, const float* __restrict__ scale_fft,
    float* __restrict__ out)
{
  __shared__ short A_lds[BM * PITCH];
  __shared__ short B_lds[BN * PITCH];

  const int tid = threadIdx.x;
  const int bx  = blockIdx.x;
  const int kc  = bx & 15;
  const int bn  = (bx >> 4) & 1;
  const int bm  = bx >> 5;
  const int i0  = kc * ICH;

  const int lane = tid & 63;
  const int wave = tid >> 6;
  const int wm   = wave & 1;
  const int wn   = wave >> 1;
  const int l15  = lane & 15;
  const int kgrp = (lane >> 4) * 8;

  f4v acc[4][4];
  #pragma unroll
  for (int a = 0; a < 4; ++a)
    #pragma unroll
    for (int b = 0; b < 4; ++b)
      acc[a][b] = (f4v){0.f, 0.f, 0.f, 0.f};

  const int row  = tid >> 1;
  const int half = tid & 1;
  const int mg   = bm * BM + row;
  const int jg   = bn * BN + row;

  const float* xrow   = x + (size_t)mg * I_DIM + i0;
  const float* fcbase = fc + (size_t)half * (O_DIM * I_DIM * G_DIM)
                           + ((size_t)jg * I_DIM + i0) * G_DIM;
  uint32_t* Arow = (uint32_t*)&A_lds[row * PITCH + half * 32];
  uint32_t* Brow = (uint32_t*)&B_lds[row * PITCH + half * 32];

  for (int it = 0; it < ICH; ++it) {
    __syncthreads();
    {
      uint32_t fb[16];
      gen_feat(xrow[it], half, fb);
      ((uint4*)Arow)[0] = make_uint4(fb[0],  fb[1],  fb[2],  fb[3]);
      ((uint4*)Arow)[1] = make_uint4(fb[4],  fb[5],  fb[6],  fb[7]);
      ((uint4*)Arow)[2] = make_uint4(fb[8],  fb[9],  fb[10], fb[11]);
      ((uint4*)Arow)[3] = make_uint4(fb[12], fb[13], fb[14], fb[15]);
    }
    {
      const int i = i0 + it;
      const size_t ij = (size_t)i * O_DIM + jg;
      const float sf  = scale_fft[ij] * mask[ij];
      const float* src = fcbase + it * G_DIM;
      uint32_t wb[16];
      #pragma unroll
      for (int q = 0; q < 8; ++q) {
        float4 v = ((const float4*)src)[q];
        wb[2*q]   = pack2bf16(v.x * sf, v.y * sf);
        wb[2*q+1] = pack2bf16(v.z * sf, v.w * sf);
      }
      ((uint4*)Brow)[0] = make_uint4(wb[0],  wb[1],  wb[2],  wb[3]);
      ((uint4*)Brow)[1] = make_uint4(wb[4],  wb[5],  wb[6],  wb[7]);
      ((uint4*)Brow)[2] = make_uint4(wb[8],  wb[9],  wb[10], wb[11]);
      ((uint4*)Brow)[3] = make_uint4(wb[12], wb[13], wb[14], wb[15]);
    }
    __syncthreads();
    #pragma unroll
    for (int ks = 0; ks < 2; ++ks) {
      s8v a[4], b[4];
      #pragma unroll
      for (int tm = 0; tm < 4; ++tm)
        a[tm] = *(const s8v*)&A_lds[(wm * 64 + tm * 16 + l15) * PITCH + ks * 32 + kgrp];
      #pragma unroll
      for (int tn = 0; tn < 4; ++tn)
        b[tn] = *(const s8v*)&B_lds[(wn * 64 + tn * 16 + l15) * PITCH + ks * 32 + kgrp];
      #pragma unroll
      for (int tm = 0; tm < 4; ++tm)
        #pragma unroll
        for (int tn = 0; tn < 4; ++tn)
          acc[tm][tn] = __builtin_amdgcn_mfma_f32_16x16x32_bf16(a[tm], b[tn], acc[tm][tn], 0, 0, 0);
    }
  }

  __syncthreads();
  {
    const float* xb = xrow + half * 8;
    float4 v0 = ((const float4*)xb)[0];
    float4 v1 = ((const float4*)xb)[1];
    uint32_t a0 = pack2bf16(silu_f(v0.x), silu_f(v0.y));
    uint32_t a1 = pack2bf16(silu_f(v0.z), silu_f(v0.w));
    uint32_t a2 = pack2bf16(silu_f(v1.x), silu_f(v1.y));
    uint32_t a3 = pack2bf16(silu_f(v1.z), silu_f(v1.w));
    ((uint4*)&A_lds[row * PITCH + half * 8])[0]      = make_uint4(a0, a1, a2, a3);
    ((uint4*)&A_lds[row * PITCH + 16 + half * 8])[0] = make_uint4(0, 0, 0, 0);
    uint32_t w[4];
    #pragma unroll
    for (int p = 0; p < 4; ++p) {
      const int ia = i0 + half * 8 + 2 * p;
      const size_t o0 = (size_t)ia * O_DIM + jg;
      const size_t o1 = o0 + O_DIM;
      w[p] = pack2bf16(scale_base[o0] * mask[o0], scale_base[o1] * mask[o1]);
    }
    ((uint4*)&B_lds[row * PITCH + half * 8])[0]      = make_uint4(w[0], w[1], w[2], w[3]);
    ((uint4*)&B_lds[row * PITCH + 16 + half * 8])[0] = make_uint4(0, 0, 0, 0);
  }
  __syncthreads();
  {
    s8v a[4], b[4];
    #pragma unroll
    for (int tm = 0; tm < 4; ++tm)
      a[tm] = *(const s8v*)&A_lds[(wm * 64 + tm * 16 + l15) * PITCH + kgrp];
    #pragma unroll
    for (int tn = 0; tn < 4; ++tn)
      b[tn] = *(const s8v*)&B_lds[(wn * 64 + tn * 16 + l15) * PITCH + kgrp];
    #pragma unroll
    for (int tm = 0; tm < 4; ++tm)
      #pragma unroll
      for (int tn = 0; tn < 4; ++tn)
        acc[tm][tn] = __builtin_amdgcn_mfma_f32_16x16x32_bf16(a[tm], b[tn], acc[tm][tn], 0, 0, 0);
  }

  const int quad = lane >> 4;
  #pragma unroll
  for (int tm = 0; tm < 4; ++tm) {
    #pragma unroll
    for (int tn = 0; tn < 4; ++tn) {
      const int n_g = bn * BN + wn * 64 + tn * 16 + l15;
      f4v v = acc[tm][tn];
      #pragma unroll
      for (int r = 0; r < 4; ++r) {
        const int m_g = bm * BM + wm * 64 + tm * 16 + quad * 4 + r;
        float val = v[r];
        if (kc == 0) val += bias[n_g];
        atomicAdd(&out[(size_t)m_g * O_DIM + n_g], val);
      }
    }
  }
}

extern "C" void kernel_launch(void* const* d_in, const int* in_sizes, int n_in,
                              void* d_out, int out_size, void* d_ws, size_t ws_size,
                              hipStream_t stream) {
  const float* x          = (const float*)d_in[0];
  const float* fc         = (const float*)d_in[1];
  const float* bias       = (const float*)d_in[2];
  const float* mask       = (const float*)d_in[3];
  const float* scale_base = (const float*)d_in[4];
  const float* scale_fft  = (const float*)d_in[5];
  float* out = (float*)d_out;

  const size_t BP_B    = (size_t)I_DIM * O_DIM * 64 * 2;        //  8,388,608
  const size_t PARTH_B = (size_t)KSPLIT * B_DIM * O_DIM * 2;    // 33,554,432

  if (ws_size >= BP_B + PARTH_B) {
    short*          Bp      = (short*)d_ws;
    unsigned short* partial = (unsigned short*)((char*)d_ws + BP_B);

    void* args[] = {(void*)&x, (void*)&fc, (void*)&bias, (void*)&mask,
                    (void*)&scale_base, (void*)&scale_fft,
                    (void*)&Bp, (void*)&partial, (void*)&out};
    hipError_t e = hipLaunchCooperativeKernel((const void*)kan_fused,
                                              dim3(1024), dim3(256),
                                              args, 0, stream);
    if (e != hipSuccess) {
      // proven 3-kernel path (R14)
      prep_bs_kernel<<<dim3(1024), dim3(256), 0, stream>>>(fc, mask, scale_fft, Bp);
      kan_main2<<<dim3(1024), dim3(256), 0, stream>>>(x, Bp, mask, scale_base, partial);
      reduce_kernel<<<dim3(512), dim3(256), 0, stream>>>(partial, bias, out);
    }
  } else {
    hipMemsetAsync(d_out, 0, (size_t)out_size * sizeof(float), stream);
    kan_fft_fallback<<<dim3(1024), dim3(256), 0, stream>>>(
        x, fc, bias, mask, scale_base, scale_fft, out);
  }
}

// Round 3
// 156.174 us; speedup vs baseline: 2.4300x; 2.4300x over previous
//
#include <hip/hip_runtime.h>
#include <stdint.h>

// out[b,j] = bias[j] + sum_i [ mask*scale_base[i,j]*silu(x[b,i])
//            + mask*scale_fft[i,j]* sum_k ( cos(kx)fc0[j,i,k] + sin(kx)fc1[j,i,k] ) ]
// R16: 2-launch pipeline. R15 post-mortem: coop grid.sync costs ~235 us on
// gfx950 (1024 blocks spinning cross-XCD) -> fused coop kernel DEAD. But the
// ~63 us residual over kernel time (stable R13/R14) is consistent with ~20 us
// per dispatch. So: eliminate the reduce dispatch + partial buffer entirely by
// atomicAdd f32 into out (fallback kernel already validates this path), and
// seed out with bias inside prep. Main loop stays byte-identical to R11/R13.
// Failed escapes (do not retry): R7 VGPR clamp (spill), R8 B-dbuf (-1 blk),
// R9 in-loop device fences (L2 inv), R12 full unroll (spill), R15 coop sync.

#define I_DIM 256
#define O_DIM 256
#define G_DIM 32
#define B_DIM 4096

#define BM 128
#define BN 128
#define KSPLIT 16
#define ICH 16                  // i's per K-chunk
#define PITCH 72                // fallback kernel only

typedef short s8v __attribute__((ext_vector_type(8)));
typedef float f4v __attribute__((ext_vector_type(4)));

__device__ __forceinline__ uint32_t pack2bf16(float a, float b) {  // RNE
  uint32_t ua = __builtin_bit_cast(uint32_t, a);
  uint32_t ub = __builtin_bit_cast(uint32_t, b);
  ua += 0x7FFFu + ((ua >> 16) & 1u);
  ub += 0x7FFFu + ((ub >> 16) & 1u);
  return (ua >> 16) | (ub & 0xFFFF0000u);
}
// round-half-up: ~half the insts of RNE; absmax impact negligible (R7/R8)
__device__ __forceinline__ uint32_t pack2bf16_f(float a, float b) {
  uint32_t ua = __builtin_bit_cast(uint32_t, a) + 0x8000u;
  uint32_t ub = __builtin_bit_cast(uint32_t, b) + 0x8000u;
  return (ua >> 16) | (ub & 0xFFFF0000u);
}
__device__ __forceinline__ float silu_f(float v) { return v / (1.0f + __expf(-v)); }

// cos/sin Chebyshev features k=1..32 for one (row, half): 16 packed uint32
__device__ __forceinline__ void gen_feat(float xv, int half, uint32_t* fb) {
  float s, c;
  __sincosf(xv, &s, &c);
  const float m2 = 2.f * c;
  float f0 = half ? s : c;                       // k=1
  float f1 = m2 * f0 - (half ? 0.f : 1.f);       // k=2
  fb[0] = pack2bf16_f(f0, f1);
  #pragma unroll
  for (int p = 1; p < 16; ++p) {
    float f2 = m2 * f1 - f0;
    float f3 = m2 * f2 - f1;
    fb[p] = pack2bf16_f(f2, f3);
    f0 = f2; f1 = f3;
  }
}

// ------------------------------------------------ prep: pack B + seed out=bias
// Bp[(i*256+j)*64 + s*8 ..] = chunk (s ^ (j&7)) of W[j,i,0:64]
// 4 threads per (i,j): (d,h). Each thread reads 64B fc, writes 2 swizzled 16B
// slots. Additionally each thread seeds 4 floats of out with bias (out is
// 1,048,576 f32 = exactly 4 per thread) so main can atomicAdd without memset.
__global__ __launch_bounds__(256) void prep_bs_kernel(
    const float* __restrict__ fc, const float* __restrict__ mask,
    const float* __restrict__ sfft, const float* __restrict__ bias,
    short* __restrict__ Bp, float* __restrict__ out)
{
  const int gid = blockIdx.x * 256 + threadIdx.x;   // 262144 threads
  const int h = gid & 1;                            // half of G row
  const int d = (gid >> 1) & 1;                     // cos / sin
  const int p = gid >> 2;                           // i*256 + j
  const int i = p >> 8, j = p & 255;
  const size_t ij = (size_t)i * O_DIM + j;
  const float sf = sfft[ij] * mask[ij];
  const float* src = fc + (size_t)d * (O_DIM * I_DIM * G_DIM)
                        + ((size_t)j * I_DIM + i) * G_DIM + h * 16;
  uint32_t w[8];
  #pragma unroll
  for (int q = 0; q < 4; ++q) {
    float4 v = ((const float4*)src)[q];
    w[2*q]   = pack2bf16(v.x * sf, v.y * sf);
    w[2*q+1] = pack2bf16(v.z * sf, v.w * sf);
  }
  uint4* dst = (uint4*)(Bp + (size_t)p * 64);
  const int xr = j & 7;
  #pragma unroll
  for (int c = 0; c < 2; ++c)
    dst[(4 * d + 2 * h + c) ^ xr] = make_uint4(w[4*c], w[4*c+1], w[4*c+2], w[4*c+3]);

  // seed out[m, n4..n4+3] = bias[n4..n4+3]
  const int n4 = (gid & 63) << 2;                   // (gid*4) % 256
  ((float4*)(out + (size_t)gid * 4))[0] = ((const float4*)(bias + n4))[0];
}

// ------------------------------------------------ main GEMM (loop byte-identical
// to R11/R13; epilogue = f32 atomicAdd to out, replacing bf16 partial stores)
__global__ __launch_bounds__(256, 4) void kan_main3(
    const float* __restrict__ x,
    const short* __restrict__ Bp,
    const float* __restrict__ mask,
    const float* __restrict__ scale_base,
    float* __restrict__ out)
{
  __shared__ short A_lds[BM * 64];        // 16 KB, XOR-chunk swizzled
  __shared__ short B_lds[BN * 64];        // 16 KB, DMA image (pre-swizzled)

  const int tid = threadIdx.x;
  const int bx  = blockIdx.x;
  const int kc  = bx & 15;                // XCD affinity: Bp slice L2-resident
  const int bn  = (bx >> 4) & 1;
  const int bm  = bx >> 5;
  const int i0  = kc * ICH;

  const int lane = tid & 63;
  const int wave = tid >> 6;
  const int wm   = wave & 1;
  const int wn   = wave >> 1;
  const int l15  = lane & 15;
  const int quad = lane >> 4;

  f4v acc[4][4];
  #pragma unroll
  for (int a = 0; a < 4; ++a)
    #pragma unroll
    for (int b = 0; b < 4; ++b)
      acc[a][b] = (f4v){0.f, 0.f, 0.f, 0.f};

  const int row  = tid >> 1;
  const int half = tid & 1;
  const int mg   = bm * BM + row;
  const int jg   = bn * BN + row;
  const int xr   = row & 7;

  const float* xrow = x + (size_t)mg * I_DIM + i0;
  uint4* Arow = (uint4*)&A_lds[row * 64];
  const int c0 = half * 4;                // this thread's 4 A-chunks
  const int q0 = wave * 4;                // 4 DMA insts per wave
  const size_t dma_lane_off = (size_t)lane * 8;

  uint32_t aNext[16];
  gen_feat(xrow[0], half, aNext);

  for (int it = 0; it < ICH; ++it) {
    __syncthreads();                      // readers of it-1 done

    // A: store regs generated during previous MFMA phase (swizzled slots)
    Arow[(c0 + 0) ^ xr] = make_uint4(aNext[0],  aNext[1],  aNext[2],  aNext[3]);
    Arow[(c0 + 1) ^ xr] = make_uint4(aNext[4],  aNext[5],  aNext[6],  aNext[7]);
    Arow[(c0 + 2) ^ xr] = make_uint4(aNext[8],  aNext[9],  aNext[10], aNext[11]);
    Arow[(c0 + 3) ^ xr] = make_uint4(aNext[12], aNext[13], aNext[14], aNext[15]);

    // B: direct HBM/L2 -> LDS DMA (after ds_writes: no alias-order stall).
    // One inst = 64 lanes x 16B = 1KB = 8 rows; 16 insts tile BN=128 rows.
    {
      const size_t rbase = ((size_t)(i0 + it) * 256 + bn * BN) * 64;
      #pragma unroll
      for (int c = 0; c < 4; ++c) {
        const int q = q0 + c;
        const short* g = Bp + rbase + (size_t)q * 8 * 64 + dma_lane_off;
        __builtin_amdgcn_global_load_lds(
            (const __attribute__((address_space(1))) void*)g,
            (__attribute__((address_space(3))) void*)&B_lds[q * 8 * 64],
            16, 0, 0);
      }
    }

    __syncthreads();                      // drains vmcnt (DMA) + lgkm (A writes)

    if (it + 1 < ICH) gen_feat(xrow[it + 1], half, aNext);  // overlaps MFMA below

    #pragma unroll
    for (int ks = 0; ks < 2; ++ks) {
      s8v a[4], b[4];
      #pragma unroll
      for (int tm = 0; tm < 4; ++tm) {
        const int r = wm * 64 + tm * 16 + l15;
        a[tm] = *(const s8v*)&A_lds[r * 64 + (((ks * 4 + quad) ^ (r & 7)) * 8)];
      }
      #pragma unroll
      for (int tn = 0; tn < 4; ++tn) {
        const int r = wn * 64 + tn * 16 + l15;
        b[tn] = *(const s8v*)&B_lds[r * 64 + (((ks * 4 + quad) ^ (r & 7)) * 8)];
      }
      #pragma unroll
      for (int tm = 0; tm < 4; ++tm)
        #pragma unroll
        for (int tn = 0; tn < 4; ++tn)
          acc[tm][tn] = __builtin_amdgcn_mfma_f32_16x16x32_bf16(a[tm], b[tn], acc[tm][tn], 0, 0, 0);
    }
  }

  // ---------------- base tile: K=32 (16 silu features + 16 zeros)
  __syncthreads();
  {
    const float* xb = xrow + half * 8;
    float4 v0 = ((const float4*)xb)[0];
    float4 v1 = ((const float4*)xb)[1];
    uint32_t a0 = pack2bf16(silu_f(v0.x), silu_f(v0.y));
    uint32_t a1 = pack2bf16(silu_f(v0.z), silu_f(v0.w));
    uint32_t a2 = pack2bf16(silu_f(v1.x), silu_f(v1.y));
    uint32_t a3 = pack2bf16(silu_f(v1.z), silu_f(v1.w));
    Arow[half ^ xr]       = make_uint4(a0, a1, a2, a3);
    Arow[(2 + half) ^ xr] = make_uint4(0, 0, 0, 0);

    uint32_t w[4];
    #pragma unroll
    for (int p = 0; p < 4; ++p) {
      const int ia = i0 + half * 8 + 2 * p;
      const size_t o0 = (size_t)ia * O_DIM + jg;
      const size_t o1 = o0 + O_DIM;
      w[p] = pack2bf16(scale_base[o0] * mask[o0], scale_base[o1] * mask[o1]);
    }
    uint4* Brow = (uint4*)&B_lds[row * 64];
    Brow[half ^ xr]       = make_uint4(w[0], w[1], w[2], w[3]);
    Brow[(2 + half) ^ xr] = make_uint4(0, 0, 0, 0);
  }
  __syncthreads();
  {
    s8v a[4], b[4];
    #pragma unroll
    for (int tm = 0; tm < 4; ++tm) {
      const int r = wm * 64 + tm * 16 + l15;
      a[tm] = *(const s8v*)&A_lds[r * 64 + ((quad ^ (r & 7)) * 8)];
    }
    #pragma unroll
    for (int tn = 0; tn < 4; ++tn) {
      const int r = wn * 64 + tn * 16 + l15;
      b[tn] = *(const s8v*)&B_lds[r * 64 + ((quad ^ (r & 7)) * 8)];
    }
    #pragma unroll
    for (int tm = 0; tm < 4; ++tm)
      #pragma unroll
      for (int tn = 0; tn < 4; ++tn)
        acc[tm][tn] = __builtin_amdgcn_mfma_f32_16x16x32_bf16(a[tm], b[tn], acc[tm][tn], 0, 0, 0);
  }

  // ---------------- epilogue: f32 atomicAdd to out (bias pre-seeded by prep).
  // Quarter-wave lanes (l15) are contiguous in n -> 64B line-granular RMWs.
  #pragma unroll
  for (int tm = 0; tm < 4; ++tm) {
    #pragma unroll
    for (int tn = 0; tn < 4; ++tn) {
      const int n_g = bn * BN + wn * 64 + tn * 16 + l15;
      f4v v = acc[tm][tn];
      #pragma unroll
      for (int r = 0; r < 4; ++r) {
        const int m_g = bm * BM + wm * 64 + tm * 16 + quad * 4 + r;
        unsafeAtomicAdd(&out[(size_t)m_g * O_DIM + n_g], v[r]);
      }
    }
  }
}

// ================================================ ws-free atomic fallback (R2)
__global__ __launch_bounds__(256, 4) void kan_fft_fallback(
    const float* __restrict__ x, const float* __restrict__ fc,
    const float* __restrict__ bias, const float* __restrict__ mask,
    const float* __restrict__ scale_base, const float* __restrict__ scale_fft,
    float* __restrict__ out)
{
  __shared__ short A_lds[BM * PITCH];
  __shared__ short B_lds[BN * PITCH];

  const int tid = threadIdx.x;
  const int bx  = blockIdx.x;
  const int kc  = bx & 15;
  const int bn  = (bx >> 4) & 1;
  const int bm  = bx >> 5;
  const int i0  = kc * ICH;

  const int lane = tid & 63;
  const int wave = tid >> 6;
  const int wm   = wave & 1;
  const int wn   = wave >> 1;
  const int l15  = lane & 15;
  const int kgrp = (lane >> 4) * 8;

  f4v acc[4][4];
  #pragma unroll
  for (int a = 0; a < 4; ++a)
    #pragma unroll
    for (int b = 0; b < 4; ++b)
      acc[a][b] = (f4v){0.f, 0.f, 0.f, 0.f};

  const int row  = tid >> 1;
  const int half = tid & 1;
  const int mg   = bm * BM + row;
  const int jg   = bn * BN + row;

  const float* xrow   = x + (size_t)mg * I_DIM + i0;
  const float* fcbase = fc + (size_t)half * (O_DIM * I_DIM * G_DIM)
                           + ((size_t)jg * I_DIM + i0) * G_DIM;
  uint32_t* Arow = (uint32_t*)&A_lds[row * PITCH + half * 32];
  uint32_t* Brow = (uint32_t*)&B_lds[row * PITCH + half * 32];

  for (int it = 0; it < ICH; ++it) {
    __syncthreads();
    {
      uint32_t fb[16];
      gen_feat(xrow[it], half, fb);
      ((uint4*)Arow)[0] = make_uint4(fb[0],  fb[1],  fb[2],  fb[3]);
      ((uint4*)Arow)[1] = make_uint4(fb[4],  fb[5],  fb[6],  fb[7]);
      ((uint4*)Arow)[2] = make_uint4(fb[8],  fb[9],  fb[10], fb[11]);
      ((uint4*)Arow)[3] = make_uint4(fb[12], fb[13], fb[14], fb[15]);
    }
    {
      const int i = i0 + it;
      const size_t ij = (size_t)i * O_DIM + jg;
      const float sf  = scale_fft[ij] * mask[ij];
      const float* src = fcbase + it * G_DIM;
      uint32_t wb[16];
      #pragma unroll
      for (int q = 0; q < 8; ++q) {
        float4 v = ((const float4*)src)[q];
        wb[2*q]   = pack2bf16(v.x * sf, v.y * sf);
        wb[2*q+1] = pack2bf16(v.z * sf, v.w * sf);
      }
      ((uint4*)Brow)[0] = make_uint4(wb[0],  wb[1],  wb[2],  wb[3]);
      ((uint4*)Brow)[1] = make_uint4(wb[4],  wb[5],  wb[6],  wb[7]);
      ((uint4*)Brow)[2] = make_uint4(wb[8],  wb[9],  wb[10], wb[11]);
      ((uint4*)Brow)[3] = make_uint4(wb[12], wb[13], wb[14], wb[15]);
    }
    __syncthreads();
    #pragma unroll
    for (int ks = 0; ks < 2; ++ks) {
      s8v a[4], b[4];
      #pragma unroll
      for (int tm = 0; tm < 4; ++tm)
        a[tm] = *(const s8v*)&A_lds[(wm * 64 + tm * 16 + l15) * PITCH + ks * 32 + kgrp];
      #pragma unroll
      for (int tn = 0; tn < 4; ++tn)
        b[tn] = *(const s8v*)&B_lds[(wn * 64 + tn * 16 + l15) * PITCH + ks * 32 + kgrp];
      #pragma unroll
      for (int tm = 0; tm < 4; ++tm)
        #pragma unroll
        for (int tn = 0; tn < 4; ++tn)
          acc[tm][tn] = __builtin_amdgcn_mfma_f32_16x16x32_bf16(a[tm], b[tn], acc[tm][tn], 0, 0, 0);
    }
  }

  __syncthreads();
  {
    const float* xb = xrow + half * 8;
    float4 v0 = ((const float4*)xb)[0];
    float4 v1 = ((const float4*)xb)[1];
    uint32_t a0 = pack2bf16(silu_f(v0.x), silu_f(v0.y));
    uint32_t a1 = pack2bf16(silu_f(v0.z), silu_f(v0.w));
    uint32_t a2 = pack2bf16(silu_f(v1.x), silu_f(v1.y));
    uint32_t a3 = pack2bf16(silu_f(v1.z), silu_f(v1.w));
    ((uint4*)&A_lds[row * PITCH + half * 8])[0]      = make_uint4(a0, a1, a2, a3);
    ((uint4*)&A_lds[row * PITCH + 16 + half * 8])[0] = make_uint4(0, 0, 0, 0);
    uint32_t w[4];
    #pragma unroll
    for (int p = 0; p < 4; ++p) {
      const int ia = i0 + half * 8 + 2 * p;
      const size_t o0 = (size_t)ia * O_DIM + jg;
      const size_t o1 = o0 + O_DIM;
      w[p] = pack2bf16(scale_base[o0] * mask[o0], scale_base[o1] * mask[o1]);
    }
    ((uint4*)&B_lds[row * PITCH + half * 8])[0]      = make_uint4(w[0], w[1], w[2], w[3]);
    ((uint4*)&B_lds[row * PITCH + 16 + half * 8])[0] = make_uint4(0, 0, 0, 0);
  }
  __syncthreads();
  {
    s8v a[4], b[4];
    #pragma unroll
    for (int tm = 0; tm < 4; ++tm)
      a[tm] = *(const s8v*)&A_lds[(wm * 64 + tm * 16 + l15) * PITCH + kgrp];
    #pragma unroll
    for (int tn = 0; tn < 4; ++tn)
      b[tn] = *(const s8v*)&B_lds[(wn * 64 + tn * 16 + l15) * PITCH + kgrp];
    #pragma unroll
    for (int tm = 0; tm < 4; ++tm)
      #pragma unroll
      for (int tn = 0; tn < 4; ++tn)
        acc[tm][tn] = __builtin_amdgcn_mfma_f32_16x16x32_bf16(a[tm], b[tn], acc[tm][tn], 0, 0, 0);
  }

  const int quad = lane >> 4;
  #pragma unroll
  for (int tm = 0; tm < 4; ++tm) {
    #pragma unroll
    for (int tn = 0; tn < 4; ++tn) {
      const int n_g = bn * BN + wn * 64 + tn * 16 + l15;
      f4v v = acc[tm][tn];
      #pragma unroll
      for (int r = 0; r < 4; ++r) {
        const int m_g = bm * BM + wm * 64 + tm * 16 + quad * 4 + r;
        float val = v[r];
        if (kc == 0) val += bias[n_g];
        atomicAdd(&out[(size_t)m_g * O_DIM + n_g], val);
      }
    }
  }
}

extern "C" void kernel_launch(void* const* d_in, const int* in_sizes, int n_in,
                              void* d_out, int out_size, void* d_ws, size_t ws_size,
                              hipStream_t stream) {
  const float* x          = (const float*)d_in[0];
  const float* fc         = (const float*)d_in[1];
  const float* bias       = (const float*)d_in[2];
  const float* mask       = (const float*)d_in[3];
  const float* scale_base = (const float*)d_in[4];
  const float* scale_fft  = (const float*)d_in[5];
  float* out = (float*)d_out;

  const size_t BP_B = (size_t)I_DIM * O_DIM * 64 * 2;           //  8,388,608

  if (ws_size >= BP_B) {
    short* Bp = (short*)d_ws;
    prep_bs_kernel<<<dim3(1024), dim3(256), 0, stream>>>(fc, mask, scale_fft, bias, Bp, out);
    kan_main3<<<dim3(1024), dim3(256), 0, stream>>>(x, Bp, mask, scale_base, out);
  } else {
    hipMemsetAsync(d_out, 0, (size_t)out_size * sizeof(float), stream);
    kan_fft_fallback<<<dim3(1024), dim3(256), 0, stream>>>(
        x, fc, bias, mask, scale_base, scale_fft, out);
  }
}

// Round 4
// 124.838 us; speedup vs baseline: 3.0399x; 1.2510x over previous
//
#include <hip/hip_runtime.h>
#include <stdint.h>

// out[b,j] = bias[j] + sum_i [ mask*scale_base[i,j]*silu(x[b,i])
//            + mask*scale_fft[i,j]* sum_k ( cos(kx)fc0[j,i,k] + sin(kx)fc1[j,i,k] ) ]
// R17: revert to R14 3-kernel structure (residual is FIXED ~65us harness
// overhead, launch-count-independent: R14 3-launch res 64us, R16 2-launch res
// 67us). Attack main's 51.8us: (a) v_cvt_pk_bf16_f32 (1 inst RNE) replaces
// 5-inst bit-pack in gen_feat (VALUBusy 36% -> biggest pipe); (b) hoist
// gen_feat(it+1) + x prefetch BEFORE barrier-2 so the DMA vmcnt(0) drain
// (~37% idle) hides feature generation instead of serializing with it.
// Failed escapes (do not retry): R7 VGPR clamp (spill), R8 B-dbuf (-1 blk),
// R9 in-loop device fences (L2 inv), R12 full unroll (spill), R15 coop
// grid.sync (~235us), R16 f32-atomic epilogue (main +30us, 64MB HBM RMW).

#define I_DIM 256
#define O_DIM 256
#define G_DIM 32
#define B_DIM 4096

#define BM 128
#define BN 128
#define KSPLIT 16
#define ICH 16                  // i's per K-chunk
#define PITCH 72                // fallback kernel only

typedef short s8v __attribute__((ext_vector_type(8)));
typedef float f4v __attribute__((ext_vector_type(4)));

__device__ __forceinline__ uint32_t pack2bf16(float a, float b) {  // RNE
  uint32_t ua = __builtin_bit_cast(uint32_t, a);
  uint32_t ub = __builtin_bit_cast(uint32_t, b);
  ua += 0x7FFFu + ((ua >> 16) & 1u);
  ub += 0x7FFFu + ((ub >> 16) & 1u);
  return (ua >> 16) | (ub & 0xFFFF0000u);
}
__device__ __forceinline__ unsigned short bf16_rne(float a) {      // RNE scalar
  uint32_t ua = __builtin_bit_cast(uint32_t, a);
  ua += 0x7FFFu + ((ua >> 16) & 1u);
  return (unsigned short)(ua >> 16);
}
// single-instruction packed f32->bf16 (RNE): lo = bf16(a), hi = bf16(b)
__device__ __forceinline__ uint32_t cvtpk_bf16(float a, float b) {
  uint32_t r;
  asm("v_cvt_pk_bf16_f32 %0, %1, %2" : "=v"(r) : "v"(a), "v"(b));
  return r;
}
__device__ __forceinline__ float silu_f(float v) { return v / (1.0f + __expf(-v)); }

// cos/sin Chebyshev features k=1..32 for one (row, half): 16 packed uint32
// R17: cvt_pk pack -> per feature pair: 2 FMA + 1 cvt (was 2 FMA + 5 bit-ops)
__device__ __forceinline__ void gen_feat(float xv, int half, uint32_t* fb) {
  float s, c;
  __sincosf(xv, &s, &c);
  const float m2 = 2.f * c;
  float f0 = half ? s : c;                       // k=1
  float f1 = m2 * f0 - (half ? 0.f : 1.f);       // k=2
  fb[0] = cvtpk_bf16(f0, f1);
  #pragma unroll
  for (int p = 1; p < 16; ++p) {
    float f2 = m2 * f1 - f0;
    float f3 = m2 * f2 - f1;
    fb[p] = cvtpk_bf16(f2, f3);
    f0 = f2; f1 = f3;
  }
}

// ------------------------------------------------ prep: pack B, i-major, XOR-swizzled
// Bp[(i*256+j)*64 + s*8 ..] = chunk (s ^ (j&7)) of W[j,i,0:64]
// 4 threads per (i,j): (d,h). Each thread reads 64B fc, writes 2 swizzled 16B slots.
__global__ __launch_bounds__(256) void prep_bs_kernel(
    const float* __restrict__ fc, const float* __restrict__ mask,
    const float* __restrict__ sfft, short* __restrict__ Bp)
{
  const int gid = blockIdx.x * 256 + threadIdx.x;   // 262144 threads
  const int h = gid & 1;                            // half of G row
  const int d = (gid >> 1) & 1;                     // cos / sin
  const int p = gid >> 2;                           // i*256 + j
  const int i = p >> 8, j = p & 255;
  const size_t ij = (size_t)i * O_DIM + j;
  const float sf = sfft[ij] * mask[ij];
  const float* src = fc + (size_t)d * (O_DIM * I_DIM * G_DIM)
                        + ((size_t)j * I_DIM + i) * G_DIM + h * 16;
  uint32_t w[8];
  #pragma unroll
  for (int q = 0; q < 4; ++q) {
    float4 v = ((const float4*)src)[q];
    w[2*q]   = pack2bf16(v.x * sf, v.y * sf);
    w[2*q+1] = pack2bf16(v.z * sf, v.w * sf);
  }
  uint4* dst = (uint4*)(Bp + (size_t)p * 64);
  const int xr = j & 7;
  #pragma unroll
  for (int c = 0; c < 2; ++c)
    dst[(4 * d + 2 * h + c) ^ xr] = make_uint4(w[4*c], w[4*c+1], w[4*c+2], w[4*c+3]);
}

// ------------------------------------------------ main GEMM
// R17 loop: bar1 | A-write(it) | DMA B(it) | gen_feat(it+1) + x prefetch
// (hidden under DMA flight) | bar2(vmcnt drain) | pure MFMA phase.
__global__ __launch_bounds__(256, 4) void kan_main4(
    const float* __restrict__ x,
    const short* __restrict__ Bp,
    const float* __restrict__ mask,
    const float* __restrict__ scale_base,
    unsigned short* __restrict__ partial) // (16, 4096, 256) bf16
{
  __shared__ short A_lds[BM * 64];        // 16 KB, XOR-chunk swizzled
  __shared__ short B_lds[BN * 64];        // 16 KB, DMA image (pre-swizzled)

  const int tid = threadIdx.x;
  const int bx  = blockIdx.x;
  const int kc  = bx & 15;                // XCD affinity: Bp slice L2-resident
  const int bn  = (bx >> 4) & 1;
  const int bm  = bx >> 5;
  const int i0  = kc * ICH;

  const int lane = tid & 63;
  const int wave = tid >> 6;
  const int wm   = wave & 1;
  const int wn   = wave >> 1;
  const int l15  = lane & 15;
  const int quad = lane >> 4;

  f4v acc[4][4];
  #pragma unroll
  for (int a = 0; a < 4; ++a)
    #pragma unroll
    for (int b = 0; b < 4; ++b)
      acc[a][b] = (f4v){0.f, 0.f, 0.f, 0.f};

  const int row  = tid >> 1;
  const int half = tid & 1;
  const int mg   = bm * BM + row;
  const int jg   = bn * BN + row;
  const int xr   = row & 7;

  const float* xrow = x + (size_t)mg * I_DIM + i0;
  uint4* Arow = (uint4*)&A_lds[row * 64];
  const int c0 = half * 4;                // this thread's 4 A-chunks
  const int q0 = wave * 4;                // 4 DMA insts per wave
  const size_t dma_lane_off = (size_t)lane * 8;

  uint32_t aNext[16];
  float xcur = xrow[0];
  gen_feat(xcur, half, aNext);
  float xnxt = xrow[1];

  for (int it = 0; it < ICH; ++it) {
    __syncthreads();                      // readers of it-1 done

    // A: store regs generated during previous iteration (swizzled slots)
    Arow[(c0 + 0) ^ xr] = make_uint4(aNext[0],  aNext[1],  aNext[2],  aNext[3]);
    Arow[(c0 + 1) ^ xr] = make_uint4(aNext[4],  aNext[5],  aNext[6],  aNext[7]);
    Arow[(c0 + 2) ^ xr] = make_uint4(aNext[8],  aNext[9],  aNext[10], aNext[11]);
    Arow[(c0 + 3) ^ xr] = make_uint4(aNext[12], aNext[13], aNext[14], aNext[15]);

    // B: direct HBM/L2 -> LDS DMA (after ds_writes: no alias-order stall).
    // One inst = 64 lanes x 16B = 1KB = 8 rows; 16 insts tile BN=128 rows.
    {
      const size_t rbase = ((size_t)(i0 + it) * 256 + bn * BN) * 64;
      #pragma unroll
      for (int c = 0; c < 4; ++c) {
        const int q = q0 + c;
        const short* g = Bp + rbase + (size_t)q * 8 * 64 + dma_lane_off;
        __builtin_amdgcn_global_load_lds(
            (const __attribute__((address_space(1))) void*)g,
            (__attribute__((address_space(3))) void*)&B_lds[q * 8 * 64],
            16, 0, 0);
      }
    }

    // gen features for it+1 NOW: executes while this wave's DMA is in flight,
    // i.e. inside the vmcnt(0)-drain shadow that precedes the barrier below.
    if (it + 1 < ICH) {
      gen_feat(xnxt, half, aNext);
      if (it + 2 < ICH) xnxt = xrow[it + 2];   // prefetch: consumed next it
    }

    __syncthreads();                      // drains vmcnt (DMA) + lgkm (A writes)

    #pragma unroll
    for (int ks = 0; ks < 2; ++ks) {
      s8v a[4], b[4];
      #pragma unroll
      for (int tm = 0; tm < 4; ++tm) {
        const int r = wm * 64 + tm * 16 + l15;
        a[tm] = *(const s8v*)&A_lds[r * 64 + (((ks * 4 + quad) ^ (r & 7)) * 8)];
      }
      #pragma unroll
      for (int tn = 0; tn < 4; ++tn) {
        const int r = wn * 64 + tn * 16 + l15;
        b[tn] = *(const s8v*)&B_lds[r * 64 + (((ks * 4 + quad) ^ (r & 7)) * 8)];
      }
      #pragma unroll
      for (int tm = 0; tm < 4; ++tm)
        #pragma unroll
        for (int tn = 0; tn < 4; ++tn)
          acc[tm][tn] = __builtin_amdgcn_mfma_f32_16x16x32_bf16(a[tm], b[tn], acc[tm][tn], 0, 0, 0);
    }
  }

  // ---------------- base tile: K=32 (16 silu features + 16 zeros)
  __syncthreads();
  {
    const float* xb = xrow + half * 8;
    float4 v0 = ((const float4*)xb)[0];
    float4 v1 = ((const float4*)xb)[1];
    uint32_t a0 = pack2bf16(silu_f(v0.x), silu_f(v0.y));
    uint32_t a1 = pack2bf16(silu_f(v0.z), silu_f(v0.w));
    uint32_t a2 = pack2bf16(silu_f(v1.x), silu_f(v1.y));
    uint32_t a3 = pack2bf16(silu_f(v1.z), silu_f(v1.w));
    Arow[half ^ xr]       = make_uint4(a0, a1, a2, a3);
    Arow[(2 + half) ^ xr] = make_uint4(0, 0, 0, 0);

    uint32_t w[4];
    #pragma unroll
    for (int p = 0; p < 4; ++p) {
      const int ia = i0 + half * 8 + 2 * p;
      const size_t o0 = (size_t)ia * O_DIM + jg;
      const size_t o1 = o0 + O_DIM;
      w[p] = pack2bf16(scale_base[o0] * mask[o0], scale_base[o1] * mask[o1]);
    }
    uint4* Brow = (uint4*)&B_lds[row * 64];
    Brow[half ^ xr]       = make_uint4(w[0], w[1], w[2], w[3]);
    Brow[(2 + half) ^ xr] = make_uint4(0, 0, 0, 0);
  }
  __syncthreads();
  {
    s8v a[4], b[4];
    #pragma unroll
    for (int tm = 0; tm < 4; ++tm) {
      const int r = wm * 64 + tm * 16 + l15;
      a[tm] = *(const s8v*)&A_lds[r * 64 + ((quad ^ (r & 7)) * 8)];
    }
    #pragma unroll
    for (int tn = 0; tn < 4; ++tn) {
      const int r = wn * 64 + tn * 16 + l15;
      b[tn] = *(const s8v*)&B_lds[r * 64 + ((quad ^ (r & 7)) * 8)];
    }
    #pragma unroll
    for (int tm = 0; tm < 4; ++tm)
      #pragma unroll
      for (int tn = 0; tn < 4; ++tn)
        acc[tm][tn] = __builtin_amdgcn_mfma_f32_16x16x32_bf16(a[tm], b[tn], acc[tm][tn], 0, 0, 0);
  }

  // ---------------- epilogue: coalesced bf16 partial stores (RNE, once/block)
  unsigned short* pbase = partial + (size_t)kc * B_DIM * O_DIM;
  #pragma unroll
  for (int tm = 0; tm < 4; ++tm) {
    #pragma unroll
    for (int tn = 0; tn < 4; ++tn) {
      const int n_g = bn * BN + wn * 64 + tn * 16 + l15;
      f4v v = acc[tm][tn];
      #pragma unroll
      for (int r = 0; r < 4; ++r) {
        const int m_g = bm * BM + wm * 64 + tm * 16 + quad * 4 + r;
        pbase[(size_t)m_g * O_DIM + n_g] = bf16_rne(v[r]);
      }
    }
  }
}

// ------------------------------------------------ reduce (bf16 partials)
// compile-time KSPLIT bound (full unroll -> 16 independent dwordx4 loads in
// flight), 16B/lane. 131072 threads, each produces 8 outputs.
__global__ __launch_bounds__(256) void reduce_kernel(
    const unsigned short* __restrict__ partial, const float* __restrict__ bias,
    float* __restrict__ out)
{
  const int g  = blockIdx.x * 256 + threadIdx.x;   // 131072 threads
  const int m  = g >> 5;
  const int n8 = (g & 31) << 3;
  const unsigned short* p = partial + (size_t)m * O_DIM + n8;

  float acc[8];
  {
    float4 b0 = ((const float4*)(bias + n8))[0];
    float4 b1 = ((const float4*)(bias + n8))[1];
    acc[0] = b0.x; acc[1] = b0.y; acc[2] = b0.z; acc[3] = b0.w;
    acc[4] = b1.x; acc[5] = b1.y; acc[6] = b1.z; acc[7] = b1.w;
  }
  #pragma unroll
  for (int kc = 0; kc < KSPLIT; ++kc) {
    const uint4 v = *(const uint4*)(p + (size_t)kc * (B_DIM * O_DIM));
    acc[0] += __builtin_bit_cast(float, v.x << 16);
    acc[1] += __builtin_bit_cast(float, v.x & 0xFFFF0000u);
    acc[2] += __builtin_bit_cast(float, v.y << 16);
    acc[3] += __builtin_bit_cast(float, v.y & 0xFFFF0000u);
    acc[4] += __builtin_bit_cast(float, v.z << 16);
    acc[5] += __builtin_bit_cast(float, v.z & 0xFFFF0000u);
    acc[6] += __builtin_bit_cast(float, v.w << 16);
    acc[7] += __builtin_bit_cast(float, v.w & 0xFFFF0000u);
  }
  float* o = out + (size_t)m * O_DIM + n8;
  ((float4*)o)[0] = make_float4(acc[0], acc[1], acc[2], acc[3]);
  ((float4*)o)[1] = make_float4(acc[4], acc[5], acc[6], acc[7]);
}

// ================================================ ws-free atomic fallback (R2)
__global__ __launch_bounds__(256, 4) void kan_fft_fallback(
    const float* __restrict__ x, const float* __restrict__ fc,
    const float* __restrict__ bias, const float* __restrict__ mask,
    const float* __restrict__ scale_base, const float* __restrict__ scale_fft,
    float* __restrict__ out)
{
  __shared__ short A_lds[BM * PITCH];
  __shared__ short B_lds[BN * PITCH];

  const int tid = threadIdx.x;
  const int bx  = blockIdx.x;
  const int kc  = bx & 15;
  const int bn  = (bx >> 4) & 1;
  const int bm  = bx >> 5;
  const int i0  = kc * ICH;

  const int lane = tid & 63;
  const int wave = tid >> 6;
  const int wm   = wave & 1;
  const int wn   = wave >> 1;
  const int l15  = lane & 15;
  const int kgrp = (lane >> 4) * 8;

  f4v acc[4][4];
  #pragma unroll
  for (int a = 0; a < 4; ++a)
    #pragma unroll
    for (int b = 0; b < 4; ++b)
      acc[a][b] = (f4v){0.f, 0.f, 0.f, 0.f};

  const int row  = tid >> 1;
  const int half = tid & 1;
  const int mg   = bm * BM + row;
  const int jg   = bn * BN + row;

  const float* xrow   = x + (size_t)mg * I_DIM + i0;
  const float* fcbase = fc + (size_t)half * (O_DIM * I_DIM * G_DIM)
                           + ((size_t)jg * I_DIM + i0) * G_DIM;
  uint32_t* Arow = (uint32_t*)&A_lds[row * PITCH + half * 32];
  uint32_t* Brow = (uint32_t*)&B_lds[row * PITCH + half * 32];

  for (int it = 0; it < ICH; ++it) {
    __syncthreads();
    {
      uint32_t fb[16];
      gen_feat(xrow[it], half, fb);
      ((uint4*)Arow)[0] = make_uint4(fb[0],  fb[1],  fb[2],  fb[3]);
      ((uint4*)Arow)[1] = make_uint4(fb[4],  fb[5],  fb[6],  fb[7]);
      ((uint4*)Arow)[2] = make_uint4(fb[8],  fb[9],  fb[10], fb[11]);
      ((uint4*)Arow)[3] = make_uint4(fb[12], fb[13], fb[14], fb[15]);
    }
    {
      const int i = i0 + it;
      const size_t ij = (size_t)i * O_DIM + jg;
      const float sf  = scale_fft[ij] * mask[ij];
      const float* src = fcbase + it * G_DIM;
      uint32_t wb[16];
      #pragma unroll
      for (int q = 0; q < 8; ++q) {
        float4 v = ((const float4*)src)[q];
        wb[2*q]   = pack2bf16(v.x * sf, v.y * sf);
        wb[2*q+1] = pack2bf16(v.z * sf, v.w * sf);
      }
      ((uint4*)Brow)[0] = make_uint4(wb[0],  wb[1],  wb[2],  wb[3]);
      ((uint4*)Brow)[1] = make_uint4(wb[4],  wb[5],  wb[6],  wb[7]);
      ((uint4*)Brow)[2] = make_uint4(wb[8],  wb[9],  wb[10], wb[11]);
      ((uint4*)Brow)[3] = make_uint4(wb[12], wb[13], wb[14], wb[15]);
    }
    __syncthreads();
    #pragma unroll
    for (int ks = 0; ks < 2; ++ks) {
      s8v a[4], b[4];
      #pragma unroll
      for (int tm = 0; tm < 4; ++tm)
        a[tm] = *(const s8v*)&A_lds[(wm * 64 + tm * 16 + l15) * PITCH + ks * 32 + kgrp];
      #pragma unroll
      for (int tn = 0; tn < 4; ++tn)
        b[tn] = *(const s8v*)&B_lds[(wn * 64 + tn * 16 + l15) * PITCH + ks * 32 + kgrp];
      #pragma unroll
      for (int tm = 0; tm < 4; ++tm)
        #pragma unroll
        for (int tn = 0; tn < 4; ++tn)
          acc[tm][tn] = __builtin_amdgcn_mfma_f32_16x16x32_bf16(a[tm], b[tn], acc[tm][tn], 0, 0, 0);
    }
  }

  __syncthreads();
  {
    const float* xb = xrow + half * 8;
    float4 v0 = ((const float4*)xb)[0];
    float4 v1 = ((const float4*)xb)[1];
    uint32_t a0 = pack2bf16(silu_f(v0.x), silu_f(v0.y));
    uint32_t a1 = pack2bf16(silu_f(v0.z), silu_f(v0.w));
    uint32_t a2 = pack2bf16(silu_f(v1.x), silu_f(v1.y));
    uint32_t a3 = pack2bf16(silu_f(v1.z), silu_f(v1.w));
    ((uint4*)&A_lds[row * PITCH + half * 8])[0]      = make_uint4(a0, a1, a2, a3);
    ((uint4*)&A_lds[row * PITCH + 16 + half * 8])[0] = make_uint4(0, 0, 0, 0);
    uint32_t w[4];
    #pragma unroll
    for (int p = 0; p < 4; ++p) {
      const int ia = i0 + half * 8 + 2 * p;
      const size_t o0 = (size_t)ia * O_DIM + jg;
      const size_t o1 = o0 + O_DIM;
      w[p] = pack2bf16(scale_base[o0] * mask[o0], scale_base[o1] * mask[o1]);
    }
    ((uint4*)&B_lds[row * PITCH + half * 8])[0]      = make_uint4(w[0], w[1], w[2], w[3]);
    ((uint4*)&B_lds[row * PITCH + 16 + half * 8])[0] = make_uint4(0, 0, 0, 0);
  }
  __syncthreads();
  {
    s8v a[4], b[4];
    #pragma unroll
    for (int tm = 0; tm < 4; ++tm)
      a[tm] = *(const s8v*)&A_lds[(wm * 64 + tm * 16 + l15) * PITCH + kgrp];
    #pragma unroll
    for (int tn = 0; tn < 4; ++tn)
      b[tn] = *(const s8v*)&B_lds[(wn * 64 + tn * 16 + l15) * PITCH + kgrp];
    #pragma unroll
    for (int tm = 0; tm < 4; ++tm)
      #pragma unroll
      for (int tn = 0; tn < 4; ++tn)
        acc[tm][tn] = __builtin_amdgcn_mfma_f32_16x16x32_bf16(a[tm], b[tn], acc[tm][tn], 0, 0, 0);
  }

  const int quad = lane >> 4;
  #pragma unroll
  for (int tm = 0; tm < 4; ++tm) {
    #pragma unroll
    for (int tn = 0; tn < 4; ++tn) {
      const int n_g = bn * BN + wn * 64 + tn * 16 + l15;
      f4v v = acc[tm][tn];
      #pragma unroll
      for (int r = 0; r < 4; ++r) {
        const int m_g = bm * BM + wm * 64 + tm * 16 + quad * 4 + r;
        float val = v[r];
        if (kc == 0) val += bias[n_g];
        atomicAdd(&out[(size_t)m_g * O_DIM + n_g], val);
      }
    }
  }
}

extern "C" void kernel_launch(void* const* d_in, const int* in_sizes, int n_in,
                              void* d_out, int out_size, void* d_ws, size_t ws_size,
                              hipStream_t stream) {
  const float* x          = (const float*)d_in[0];
  const float* fc         = (const float*)d_in[1];
  const float* bias       = (const float*)d_in[2];
  const float* mask       = (const float*)d_in[3];
  const float* scale_base = (const float*)d_in[4];
  const float* scale_fft  = (const float*)d_in[5];
  float* out = (float*)d_out;

  const size_t BP_B    = (size_t)I_DIM * O_DIM * 64 * 2;        //  8,388,608
  const size_t PARTH_B = (size_t)KSPLIT * B_DIM * O_DIM * 2;    // 33,554,432

  if (ws_size >= BP_B + PARTH_B) {
    short*          Bp      = (short*)d_ws;
    unsigned short* partial = (unsigned short*)((char*)d_ws + BP_B);
    prep_bs_kernel<<<dim3(1024), dim3(256), 0, stream>>>(fc, mask, scale_fft, Bp);
    kan_main4<<<dim3(1024), dim3(256), 0, stream>>>(x, Bp, mask, scale_base, partial);
    reduce_kernel<<<dim3(512), dim3(256), 0, stream>>>(partial, bias, out);
  } else {
    hipMemsetAsync(d_out, 0, (size_t)out_size * sizeof(float), stream);
    kan_fft_fallback<<<dim3(1024), dim3(256), 0, stream>>>(
        x, fc, bias, mask, scale_base, scale_fft, out);
  }
}

// Round 5
// 121.937 us; speedup vs baseline: 3.1123x; 1.0238x over previous
//
#include <hip/hip_runtime.h>
#include <stdint.h>

// out[b,j] = bias[j] + sum_i [ mask*scale_base[i,j]*silu(x[b,i])
//            + mask*scale_fft[i,j]* sum_k ( cos(kx)fc0[j,i,k] + sin(kx)fc1[j,i,k] ) ]
// R18 = R17 + s_setprio(1) around the MFMA phases (T5). Mechanism: 4
// independent blocks/CU are at different barrier phases; setprio makes
// compute-phase waves win issue arbitration over staging-phase waves.
// R17 post-mortem: fixed harness overhead ~66us (launch-count-independent,
// R14/R16/R17 residuals 64/67/66). Main's pipes: MFMA 31% (14us floor),
// VALU 30%, LDS ~60-70% busy (96KB/block-iter -> ~32us floor). Structure
// floor ~= 66 + 32 + 13 = ~111us total.
// Failed escapes (do not retry): R7 VGPR clamp (spill), R8 B-dbuf (-1 blk),
// R9 in-loop device fences (L2 inv), R12 full unroll (spill), R15 coop
// grid.sync (~235us), R16 f32-atomic epilogue (main +30us, 64MB HBM RMW).
// Geometry is locked: 128x128 block/64x64 waves minimizes LDS bytes/FLOP;
// grid 1024 = 16kc x 2bn x 32bm = exactly 4 blocks/CU at 32KB LDS.

#define I_DIM 256
#define O_DIM 256
#define G_DIM 32
#define B_DIM 4096

#define BM 128
#define BN 128
#define KSPLIT 16
#define ICH 16                  // i's per K-chunk
#define PITCH 72                // fallback kernel only

typedef short s8v __attribute__((ext_vector_type(8)));
typedef float f4v __attribute__((ext_vector_type(4)));

__device__ __forceinline__ uint32_t pack2bf16(float a, float b) {  // RNE
  uint32_t ua = __builtin_bit_cast(uint32_t, a);
  uint32_t ub = __builtin_bit_cast(uint32_t, b);
  ua += 0x7FFFu + ((ua >> 16) & 1u);
  ub += 0x7FFFu + ((ub >> 16) & 1u);
  return (ua >> 16) | (ub & 0xFFFF0000u);
}
__device__ __forceinline__ unsigned short bf16_rne(float a) {      // RNE scalar
  uint32_t ua = __builtin_bit_cast(uint32_t, a);
  ua += 0x7FFFu + ((ua >> 16) & 1u);
  return (unsigned short)(ua >> 16);
}
// single-instruction packed f32->bf16 (RNE): lo = bf16(a), hi = bf16(b)
__device__ __forceinline__ uint32_t cvtpk_bf16(float a, float b) {
  uint32_t r;
  asm("v_cvt_pk_bf16_f32 %0, %1, %2" : "=v"(r) : "v"(a), "v"(b));
  return r;
}
__device__ __forceinline__ float silu_f(float v) { return v / (1.0f + __expf(-v)); }

// cos/sin Chebyshev features k=1..32 for one (row, half): 16 packed uint32
// per feature pair: 2 FMA + 1 cvt_pk (R17)
__device__ __forceinline__ void gen_feat(float xv, int half, uint32_t* fb) {
  float s, c;
  __sincosf(xv, &s, &c);
  const float m2 = 2.f * c;
  float f0 = half ? s : c;                       // k=1
  float f1 = m2 * f0 - (half ? 0.f : 1.f);       // k=2
  fb[0] = cvtpk_bf16(f0, f1);
  #pragma unroll
  for (int p = 1; p < 16; ++p) {
    float f2 = m2 * f1 - f0;
    float f3 = m2 * f2 - f1;
    fb[p] = cvtpk_bf16(f2, f3);
    f0 = f2; f1 = f3;
  }
}

// ------------------------------------------------ prep: pack B, i-major, XOR-swizzled
// Bp[(i*256+j)*64 + s*8 ..] = chunk (s ^ (j&7)) of W[j,i,0:64]
// 4 threads per (i,j): (d,h). Each thread reads 64B fc, writes 2 swizzled 16B slots.
__global__ __launch_bounds__(256) void prep_bs_kernel(
    const float* __restrict__ fc, const float* __restrict__ mask,
    const float* __restrict__ sfft, short* __restrict__ Bp)
{
  const int gid = blockIdx.x * 256 + threadIdx.x;   // 262144 threads
  const int h = gid & 1;                            // half of G row
  const int d = (gid >> 1) & 1;                     // cos / sin
  const int p = gid >> 2;                           // i*256 + j
  const int i = p >> 8, j = p & 255;
  const size_t ij = (size_t)i * O_DIM + j;
  const float sf = sfft[ij] * mask[ij];
  const float* src = fc + (size_t)d * (O_DIM * I_DIM * G_DIM)
                        + ((size_t)j * I_DIM + i) * G_DIM + h * 16;
  uint32_t w[8];
  #pragma unroll
  for (int q = 0; q < 4; ++q) {
    float4 v = ((const float4*)src)[q];
    w[2*q]   = pack2bf16(v.x * sf, v.y * sf);
    w[2*q+1] = pack2bf16(v.z * sf, v.w * sf);
  }
  uint4* dst = (uint4*)(Bp + (size_t)p * 64);
  const int xr = j & 7;
  #pragma unroll
  for (int c = 0; c < 2; ++c)
    dst[(4 * d + 2 * h + c) ^ xr] = make_uint4(w[4*c], w[4*c+1], w[4*c+2], w[4*c+3]);
}

// ------------------------------------------------ main GEMM
// loop: bar1 | A-write(it) | DMA B(it) | gen_feat(it+1) (hidden under DMA
// flight) | bar2(vmcnt drain) | setprio(1) MFMA phase setprio(0).
__global__ __launch_bounds__(256, 4) void kan_main5(
    const float* __restrict__ x,
    const short* __restrict__ Bp,
    const float* __restrict__ mask,
    const float* __restrict__ scale_base,
    unsigned short* __restrict__ partial) // (16, 4096, 256) bf16
{
  __shared__ short A_lds[BM * 64];        // 16 KB, XOR-chunk swizzled
  __shared__ short B_lds[BN * 64];        // 16 KB, DMA image (pre-swizzled)

  const int tid = threadIdx.x;
  const int bx  = blockIdx.x;
  const int kc  = bx & 15;                // XCD affinity: Bp slice L2-resident
  const int bn  = (bx >> 4) & 1;
  const int bm  = bx >> 5;
  const int i0  = kc * ICH;

  const int lane = tid & 63;
  const int wave = tid >> 6;
  const int wm   = wave & 1;
  const int wn   = wave >> 1;
  const int l15  = lane & 15;
  const int quad = lane >> 4;

  f4v acc[4][4];
  #pragma unroll
  for (int a = 0; a < 4; ++a)
    #pragma unroll
    for (int b = 0; b < 4; ++b)
      acc[a][b] = (f4v){0.f, 0.f, 0.f, 0.f};

  const int row  = tid >> 1;
  const int half = tid & 1;
  const int mg   = bm * BM + row;
  const int jg   = bn * BN + row;
  const int xr   = row & 7;

  const float* xrow = x + (size_t)mg * I_DIM + i0;
  uint4* Arow = (uint4*)&A_lds[row * 64];
  const int c0 = half * 4;                // this thread's 4 A-chunks
  const int q0 = wave * 4;                // 4 DMA insts per wave
  const size_t dma_lane_off = (size_t)lane * 8;

  uint32_t aNext[16];
  gen_feat(xrow[0], half, aNext);
  float xnxt = xrow[1];

  for (int it = 0; it < ICH; ++it) {
    __syncthreads();                      // readers of it-1 done

    // A: store regs generated during previous iteration (swizzled slots)
    Arow[(c0 + 0) ^ xr] = make_uint4(aNext[0],  aNext[1],  aNext[2],  aNext[3]);
    Arow[(c0 + 1) ^ xr] = make_uint4(aNext[4],  aNext[5],  aNext[6],  aNext[7]);
    Arow[(c0 + 2) ^ xr] = make_uint4(aNext[8],  aNext[9],  aNext[10], aNext[11]);
    Arow[(c0 + 3) ^ xr] = make_uint4(aNext[12], aNext[13], aNext[14], aNext[15]);

    // B: direct HBM/L2 -> LDS DMA (after ds_writes: no alias-order stall).
    // One inst = 64 lanes x 16B = 1KB = 8 rows; 16 insts tile BN=128 rows.
    {
      const size_t rbase = ((size_t)(i0 + it) * 256 + bn * BN) * 64;
      #pragma unroll
      for (int c = 0; c < 4; ++c) {
        const int q = q0 + c;
        const short* g = Bp + rbase + (size_t)q * 8 * 64 + dma_lane_off;
        __builtin_amdgcn_global_load_lds(
            (const __attribute__((address_space(1))) void*)g,
            (__attribute__((address_space(3))) void*)&B_lds[q * 8 * 64],
            16, 0, 0);
      }
    }

    // gen features for it+1 NOW: executes while this wave's DMA is in flight,
    // i.e. inside the vmcnt(0)-drain shadow that precedes the barrier below.
    if (it + 1 < ICH) {
      gen_feat(xnxt, half, aNext);
      if (it + 2 < ICH) xnxt = xrow[it + 2];   // prefetch: consumed next it
    }

    __syncthreads();                      // drains vmcnt (DMA) + lgkm (A writes)

    // T5: favor compute-phase waves over other blocks' staging-phase waves
    __builtin_amdgcn_s_setprio(1);
    #pragma unroll
    for (int ks = 0; ks < 2; ++ks) {
      s8v a[4], b[4];
      #pragma unroll
      for (int tm = 0; tm < 4; ++tm) {
        const int r = wm * 64 + tm * 16 + l15;
        a[tm] = *(const s8v*)&A_lds[r * 64 + (((ks * 4 + quad) ^ (r & 7)) * 8)];
      }
      #pragma unroll
      for (int tn = 0; tn < 4; ++tn) {
        const int r = wn * 64 + tn * 16 + l15;
        b[tn] = *(const s8v*)&B_lds[r * 64 + (((ks * 4 + quad) ^ (r & 7)) * 8)];
      }
      #pragma unroll
      for (int tm = 0; tm < 4; ++tm)
        #pragma unroll
        for (int tn = 0; tn < 4; ++tn)
          acc[tm][tn] = __builtin_amdgcn_mfma_f32_16x16x32_bf16(a[tm], b[tn], acc[tm][tn], 0, 0, 0);
    }
    __builtin_amdgcn_s_setprio(0);
  }

  // ---------------- base tile: K=32 (16 silu features + 16 zeros)
  __syncthreads();
  {
    const float* xb = xrow + half * 8;
    float4 v0 = ((const float4*)xb)[0];
    float4 v1 = ((const float4*)xb)[1];
    uint32_t a0 = pack2bf16(silu_f(v0.x), silu_f(v0.y));
    uint32_t a1 = pack2bf16(silu_f(v0.z), silu_f(v0.w));
    uint32_t a2 = pack2bf16(silu_f(v1.x), silu_f(v1.y));
    uint32_t a3 = pack2bf16(silu_f(v1.z), silu_f(v1.w));
    Arow[half ^ xr]       = make_uint4(a0, a1, a2, a3);
    Arow[(2 + half) ^ xr] = make_uint4(0, 0, 0, 0);

    uint32_t w[4];
    #pragma unroll
    for (int p = 0; p < 4; ++p) {
      const int ia = i0 + half * 8 + 2 * p;
      const size_t o0 = (size_t)ia * O_DIM + jg;
      const size_t o1 = o0 + O_DIM;
      w[p] = pack2bf16(scale_base[o0] * mask[o0], scale_base[o1] * mask[o1]);
    }
    uint4* Brow = (uint4*)&B_lds[row * 64];
    Brow[half ^ xr]       = make_uint4(w[0], w[1], w[2], w[3]);
    Brow[(2 + half) ^ xr] = make_uint4(0, 0, 0, 0);
  }
  __syncthreads();
  {
    __builtin_amdgcn_s_setprio(1);
    s8v a[4], b[4];
    #pragma unroll
    for (int tm = 0; tm < 4; ++tm) {
      const int r = wm * 64 + tm * 16 + l15;
      a[tm] = *(const s8v*)&A_lds[r * 64 + ((quad ^ (r & 7)) * 8)];
    }
    #pragma unroll
    for (int tn = 0; tn < 4; ++tn) {
      const int r = wn * 64 + tn * 16 + l15;
      b[tn] = *(const s8v*)&B_lds[r * 64 + ((quad ^ (r & 7)) * 8)];
    }
    #pragma unroll
    for (int tm = 0; tm < 4; ++tm)
      #pragma unroll
      for (int tn = 0; tn < 4; ++tn)
        acc[tm][tn] = __builtin_amdgcn_mfma_f32_16x16x32_bf16(a[tm], b[tn], acc[tm][tn], 0, 0, 0);
    __builtin_amdgcn_s_setprio(0);
  }

  // ---------------- epilogue: coalesced bf16 partial stores (RNE, once/block)
  unsigned short* pbase = partial + (size_t)kc * B_DIM * O_DIM;
  #pragma unroll
  for (int tm = 0; tm < 4; ++tm) {
    #pragma unroll
    for (int tn = 0; tn < 4; ++tn) {
      const int n_g = bn * BN + wn * 64 + tn * 16 + l15;
      f4v v = acc[tm][tn];
      #pragma unroll
      for (int r = 0; r < 4; ++r) {
        const int m_g = bm * BM + wm * 64 + tm * 16 + quad * 4 + r;
        pbase[(size_t)m_g * O_DIM + n_g] = bf16_rne(v[r]);
      }
    }
  }
}

// ------------------------------------------------ reduce (bf16 partials)
// compile-time KSPLIT bound (full unroll -> 16 independent dwordx4 loads in
// flight), 16B/lane. 131072 threads, each produces 8 outputs.
__global__ __launch_bounds__(256) void reduce_kernel(
    const unsigned short* __restrict__ partial, const float* __restrict__ bias,
    float* __restrict__ out)
{
  const int g  = blockIdx.x * 256 + threadIdx.x;   // 131072 threads
  const int m  = g >> 5;
  const int n8 = (g & 31) << 3;
  const unsigned short* p = partial + (size_t)m * O_DIM + n8;

  float acc[8];
  {
    float4 b0 = ((const float4*)(bias + n8))[0];
    float4 b1 = ((const float4*)(bias + n8))[1];
    acc[0] = b0.x; acc[1] = b0.y; acc[2] = b0.z; acc[3] = b0.w;
    acc[4] = b1.x; acc[5] = b1.y; acc[6] = b1.z; acc[7] = b1.w;
  }
  #pragma unroll
  for (int kc = 0; kc < KSPLIT; ++kc) {
    const uint4 v = *(const uint4*)(p + (size_t)kc * (B_DIM * O_DIM));
    acc[0] += __builtin_bit_cast(float, v.x << 16);
    acc[1] += __builtin_bit_cast(float, v.x & 0xFFFF0000u);
    acc[2] += __builtin_bit_cast(float, v.y << 16);
    acc[3] += __builtin_bit_cast(float, v.y & 0xFFFF0000u);
    acc[4] += __builtin_bit_cast(float, v.z << 16);
    acc[5] += __builtin_bit_cast(float, v.z & 0xFFFF0000u);
    acc[6] += __builtin_bit_cast(float, v.w << 16);
    acc[7] += __builtin_bit_cast(float, v.w & 0xFFFF0000u);
  }
  float* o = out + (size_t)m * O_DIM + n8;
  ((float4*)o)[0] = make_float4(acc[0], acc[1], acc[2], acc[3]);
  ((float4*)o)[1] = make_float4(acc[4], acc[5], acc[6], acc[7]);
}

// ================================================ ws-free atomic fallback (R2)
__global__ __launch_bounds__(256, 4) void kan_fft_fallback(
    const float* __restrict__ x, const float* __restrict__ fc,
    const float* __restrict__ bias, const float* __restrict__ mask,
    const float* __restrict__ scale_base, const float* __restrict__ scale_fft,
    float* __restrict__ out)
{
  __shared__ short A_lds[BM * PITCH];
  __shared__ short B_lds[BN * PITCH];

  const int tid = threadIdx.x;
  const int bx  = blockIdx.x;
  const int kc  = bx & 15;
  const int bn  = (bx >> 4) & 1;
  const int bm  = bx >> 5;
  const int i0  = kc * ICH;

  const int lane = tid & 63;
  const int wave = tid >> 6;
  const int wm   = wave & 1;
  const int wn   = wave >> 1;
  const int l15  = lane & 15;
  const int kgrp = (lane >> 4) * 8;

  f4v acc[4][4];
  #pragma unroll
  for (int a = 0; a < 4; ++a)
    #pragma unroll
    for (int b = 0; b < 4; ++b)
      acc[a][b] = (f4v){0.f, 0.f, 0.f, 0.f};

  const int row  = tid >> 1;
  const int half = tid & 1;
  const int mg   = bm * BM + row;
  const int jg   = bn * BN + row;

  const float* xrow   = x + (size_t)mg * I_DIM + i0;
  const float* fcbase = fc + (size_t)half * (O_DIM * I_DIM * G_DIM)
                           + ((size_t)jg * I_DIM + i0) * G_DIM;
  uint32_t* Arow = (uint32_t*)&A_lds[row * PITCH + half * 32];
  uint32_t* Brow = (uint32_t*)&B_lds[row * PITCH + half * 32];

  for (int it = 0; it < ICH; ++it) {
    __syncthreads();
    {
      uint32_t fb[16];
      gen_feat(xrow[it], half, fb);
      ((uint4*)Arow)[0] = make_uint4(fb[0],  fb[1],  fb[2],  fb[3]);
      ((uint4*)Arow)[1] = make_uint4(fb[4],  fb[5],  fb[6],  fb[7]);
      ((uint4*)Arow)[2] = make_uint4(fb[8],  fb[9],  fb[10], fb[11]);
      ((uint4*)Arow)[3] = make_uint4(fb[12], fb[13], fb[14], fb[15]);
    }
    {
      const int i = i0 + it;
      const size_t ij = (size_t)i * O_DIM + jg;
      const float sf  = scale_fft[ij] * mask[ij];
      const float* src = fcbase + it * G_DIM;
      uint32_t wb[16];
      #pragma unroll
      for (int q = 0; q < 8; ++q) {
        float4 v = ((const float4*)src)[q];
        wb[2*q]   = pack2bf16(v.x * sf, v.y * sf);
        wb[2*q+1] = pack2bf16(v.z * sf, v.w * sf);
      }
      ((uint4*)Brow)[0] = make_uint4(wb[0],  wb[1],  wb[2],  wb[3]);
      ((uint4*)Brow)[1] = make_uint4(wb[4],  wb[5],  wb[6],  wb[7]);
      ((uint4*)Brow)[2] = make_uint4(wb[8],  wb[9],  wb[10], wb[11]);
      ((uint4*)Brow)[3] = make_uint4(wb[12], wb[13], wb[14], wb[15]);
    }
    __syncthreads();
    #pragma unroll
    for (int ks = 0; ks < 2; ++ks) {
      s8v a[4], b[4];
      #pragma unroll
      for (int tm = 0; tm < 4; ++tm)
        a[tm] = *(const s8v*)&A_lds[(wm * 64 + tm * 16 + l15) * PITCH + ks * 32 + kgrp];
      #pragma unroll
      for (int tn = 0; tn < 4; ++tn)
        b[tn] = *(const s8v*)&B_lds[(wn * 64 + tn * 16 + l15) * PITCH + ks * 32 + kgrp];
      #pragma unroll
      for (int tm = 0; tm < 4; ++tm)
        #pragma unroll
        for (int tn = 0; tn < 4; ++tn)
          acc[tm][tn] = __builtin_amdgcn_mfma_f32_16x16x32_bf16(a[tm], b[tn], acc[tm][tn], 0, 0, 0);
    }
  }

  __syncthreads();
  {
    const float* xb = xrow + half * 8;
    float4 v0 = ((const float4*)xb)[0];
    float4 v1 = ((const float4*)xb)[1];
    uint32_t a0 = pack2bf16(silu_f(v0.x), silu_f(v0.y));
    uint32_t a1 = pack2bf16(silu_f(v0.z), silu_f(v0.w));
    uint32_t a2 = pack2bf16(silu_f(v1.x), silu_f(v1.y));
    uint32_t a3 = pack2bf16(silu_f(v1.z), silu_f(v1.w));
    ((uint4*)&A_lds[row * PITCH + half * 8])[0]      = make_uint4(a0, a1, a2, a3);
    ((uint4*)&A_lds[row * PITCH + 16 + half * 8])[0] = make_uint4(0, 0, 0, 0);
    uint32_t w[4];
    #pragma unroll
    for (int p = 0; p < 4; ++p) {
      const int ia = i0 + half * 8 + 2 * p;
      const size_t o0 = (size_t)ia * O_DIM + jg;
      const size_t o1 = o0 + O_DIM;
      w[p] = pack2bf16(scale_base[o0] * mask[o0], scale_base[o1] * mask[o1]);
    }
    ((uint4*)&B_lds[row * PITCH + half * 8])[0]      = make_uint4(w[0], w[1], w[2], w[3]);
    ((uint4*)&B_lds[row * PITCH + 16 + half * 8])[0] = make_uint4(0, 0, 0, 0);
  }
  __syncthreads();
  {
    s8v a[4], b[4];
    #pragma unroll
    for (int tm = 0; tm < 4; ++tm)
      a[tm] = *(const s8v*)&A_lds[(wm * 64 + tm * 16 + l15) * PITCH + kgrp];
    #pragma unroll
    for (int tn = 0; tn < 4; ++tn)
      b[tn] = *(const s8v*)&B_lds[(wn * 64 + tn * 16 + l15) * PITCH + kgrp];
    #pragma unroll
    for (int tm = 0; tm < 4; ++tm)
      #pragma unroll
      for (int tn = 0; tn < 4; ++tn)
        acc[tm][tn] = __builtin_amdgcn_mfma_f32_16x16x32_bf16(a[tm], b[tn], acc[tm][tn], 0, 0, 0);
  }

  const int quad = lane >> 4;
  #pragma unroll
  for (int tm = 0; tm < 4; ++tm) {
    #pragma unroll
    for (int tn = 0; tn < 4; ++tn) {
      const int n_g = bn * BN + wn * 64 + tn * 16 + l15;
      f4v v = acc[tm][tn];
      #pragma unroll
      for (int r = 0; r < 4; ++r) {
        const int m_g = bm * BM + wm * 64 + tm * 16 + quad * 4 + r;
        float val = v[r];
        if (kc == 0) val += bias[n_g];
        atomicAdd(&out[(size_t)m_g * O_DIM + n_g], val);
      }
    }
  }
}

extern "C" void kernel_launch(void* const* d_in, const int* in_sizes, int n_in,
                              void* d_out, int out_size, void* d_ws, size_t ws_size,
                              hipStream_t stream) {
  const float* x          = (const float*)d_in[0];
  const float* fc         = (const float*)d_in[1];
  const float* bias       = (const float*)d_in[2];
  const float* mask       = (const float*)d_in[3];
  const float* scale_base = (const float*)d_in[4];
  const float* scale_fft  = (const float*)d_in[5];
  float* out = (float*)d_out;

  const size_t BP_B    = (size_t)I_DIM * O_DIM * 64 * 2;        //  8,388,608
  const size_t PARTH_B = (size_t)KSPLIT * B_DIM * O_DIM * 2;    // 33,554,432

  if (ws_size >= BP_B + PARTH_B) {
    short*          Bp      = (short*)d_ws;
    unsigned short* partial = (unsigned short*)((char*)d_ws + BP_B);
    prep_bs_kernel<<<dim3(1024), dim3(256), 0, stream>>>(fc, mask, scale_fft, Bp);
    kan_main5<<<dim3(1024), dim3(256), 0, stream>>>(x, Bp, mask, scale_base, partial);
    reduce_kernel<<<dim3(512), dim3(256), 0, stream>>>(partial, bias, out);
  } else {
    hipMemsetAsync(d_out, 0, (size_t)out_size * sizeof(float), stream);
    kan_fft_fallback<<<dim3(1024), dim3(256), 0, stream>>>(
        x, fc, bias, mask, scale_base, scale_fft, out);
  }
}